// Round 2
// baseline (416.628 us; speedup 1.0000x reference)
//
#include <hip/hip_runtime.h>
#include <math.h>

#define T_STEPS 1024
#define BATCH   32
#define DIM     1024
#define NST     64
#define TBN     ((size_t)T_STEPS * BATCH * NST)   // 2M elements per projection

typedef __attribute__((ext_vector_type(8))) short bf16x8;
typedef __attribute__((ext_vector_type(4))) float f32x4;

#define NLOG2E (-1.44269504088896340736f)

// ======================= Phase 1: hi/lo bf16 MFMA GEMM, global_load_lds 2-phase =======================
// Same structure as round 1 (this kernel is small, <20us). One change: the ax plane (nq==3)
// is stored as  -log2e * (ax + b_alpha)  so the scan's sigmoid needs no chain-side scale.

__device__ __forceinline__ void gload16(const float* g, float* l)
{
    __builtin_amdgcn_global_load_lds(
        (const __attribute__((address_space(1))) unsigned int*)g,
        (__attribute__((address_space(3))) unsigned int*)l, 16, 0, 0);
}

__device__ __forceinline__ void cvt8(float4 v0, float4 v1, bf16x8& hi, bf16x8& lo)
{
    float f[8] = {v0.x, v0.y, v0.z, v0.w, v1.x, v1.y, v1.z, v1.w};
    bf16x8 h, l;
    #pragma unroll
    for (int i = 0; i < 8; i++) {
        unsigned b = __float_as_uint(f[i]);
        h[i] = (short)(b >> 16);                          // hi = truncate to bf16
        l[i] = (short)(__float_as_uint(f[i] - __uint_as_float(b & 0xffff0000u)) >> 16);
    }
    hi = h; lo = l;
}

__global__ __launch_bounds__(512, 1)
void proj_gemm_v2(const float* __restrict__ x,
                  const float* __restrict__ Wk,
                  const float* __restrict__ Wv,
                  const float* __restrict__ Wq,
                  const float* __restrict__ Wa,
                  const float* __restrict__ b_alpha,
                  float* __restrict__ ws)
{
    __shared__ float As[2][128][32];   // 32 KB
    __shared__ float Bs[2][256][32];   // 64 KB

    const int tid  = threadIdx.x;
    const int lane = tid & 63;
    const int w    = tid >> 6;          // wave 0..7
    const int m0   = blockIdx.x * 128;

    // staging: LDS pos p of row r holds GLOBAL granule p ^ (r&7)
    const int lrow  = lane >> 3;
    const int lgran = (lane & 7) ^ lrow;
    const float* ap0 = x + (size_t)(m0 + 16*w +     lrow) * DIM + lgran * 4;
    const float* ap1 = x + (size_t)(m0 + 16*w + 8 + lrow) * DIM + lgran * 4;
    const float* Wsrc = (w < 2) ? Wk : (w < 4) ? Wv : (w < 6) ? Wq : Wa;
    const float* bp0 = Wsrc + (size_t)((w & 1)*32 +  0 + lrow) * DIM + lgran * 4;
    const float* bp1 = Wsrc + (size_t)((w & 1)*32 +  8 + lrow) * DIM + lgran * 4;
    const float* bp2 = Wsrc + (size_t)((w & 1)*32 + 16 + lrow) * DIM + lgran * 4;
    const float* bp3 = Wsrc + (size_t)((w & 1)*32 + 24 + lrow) * DIM + lgran * 4;

    auto stage = [&](int kb, int buf) {
        const int ko = kb * 32;
        gload16(ap0 + ko, &As[buf][16*w     ][0]);
        gload16(ap1 + ko, &As[buf][16*w +  8][0]);
        gload16(bp0 + ko, &Bs[buf][32*w     ][0]);
        gload16(bp1 + ko, &Bs[buf][32*w +  8][0]);
        gload16(bp2 + ko, &Bs[buf][32*w + 16][0]);
        gload16(bp3 + ko, &Bs[buf][32*w + 24][0]);
    };

    const int fr = lane & 15;
    const int qi = lane >> 4;
    const int sx = fr & 7;
    const int mh = w >> 2;
    const int nq = w & 3;

    f32x4 acc[4][4];
    #pragma unroll
    for (int i = 0; i < 4; i++)
        #pragma unroll
        for (int j = 0; j < 4; j++)
            acc[i][j] = (f32x4)0.0f;

    stage(0, 0);
    __syncthreads();

    #pragma unroll 1
    for (int kb = 0; kb < 32; kb++) {
        const int buf = kb & 1;
        if (kb + 1 < 32) stage(kb + 1, buf ^ 1);

        bf16x8 ah[4], al[4], bh[4], bl[4];
        #pragma unroll
        for (int mt = 0; mt < 4; mt++) {
            const float* rp = &As[buf][mh*64 + mt*16 + fr][0];
            float4 v0 = *(const float4*)(rp + (((2*qi    ) ^ sx) * 4));
            float4 v1 = *(const float4*)(rp + (((2*qi + 1) ^ sx) * 4));
            cvt8(v0, v1, ah[mt], al[mt]);
        }
        #pragma unroll
        for (int nt = 0; nt < 4; nt++) {
            const float* rp = &Bs[buf][nq*64 + nt*16 + fr][0];
            float4 v0 = *(const float4*)(rp + (((2*qi    ) ^ sx) * 4));
            float4 v1 = *(const float4*)(rp + (((2*qi + 1) ^ sx) * 4));
            cvt8(v0, v1, bh[nt], bl[nt]);
        }
        #pragma unroll
        for (int mt = 0; mt < 4; mt++)
            #pragma unroll
            for (int nt = 0; nt < 4; nt++) {
                acc[mt][nt] = __builtin_amdgcn_mfma_f32_16x16x32_bf16(ah[mt], bh[nt], acc[mt][nt], 0, 0, 0);
                acc[mt][nt] = __builtin_amdgcn_mfma_f32_16x16x32_bf16(al[mt], bh[nt], acc[mt][nt], 0, 0, 0);
                acc[mt][nt] = __builtin_amdgcn_mfma_f32_16x16x32_bf16(ah[mt], bl[nt], acc[mt][nt], 0, 0, 0);
            }

        __syncthreads();
    }

    // epilogue: ax plane stored pre-scaled: -log2e*(ax + b_alpha)
    float* outb = ws + (size_t)nq * TBN;
    const int r0 = qi * 4;
    float bav[4];
    #pragma unroll
    for (int nt = 0; nt < 4; nt++)
        bav[nt] = (nq == 3) ? b_alpha[nt*16 + fr] : 0.0f;
    const float scl = (nq == 3) ? NLOG2E : 1.0f;
    #pragma unroll
    for (int mt = 0; mt < 4; mt++)
        #pragma unroll
        for (int nt = 0; nt < 4; nt++)
            #pragma unroll
            for (int r = 0; r < 4; r++)
                outb[(size_t)(m0 + mh*64 + mt*16 + r0 + r) * NST + nt*16 + fr]
                    = (acc[mt][nt][r] + bav[nt]) * scl;
}

// ======================= Phase 2: sequential scan, 2-level deferred form =======================
// ret_{t+1} = a_t*P_{t+1} + (1-a_t)*v_t*dd[t],  P_{t+1} = a_{t-1}*Q_{t+1} + (1-a_{t-1})*v_{t-1}*ee[t-1],
// Q_{t+1} = S_{t-2}.k_{t+1}  (partial+reduce issued one FULL step before consumption),
// dd[s]=k_s.k_{s+1}, ee[s]=k_s.k_{s+2} hoisted per chunk into REGISTERS.
// Critical chain per step = fma(ret) -> fma(z) -> exp2 -> add -> rcp -> alpha  (~5 ops).
// h-reduces batched 4-wide (interleaved DPP chains); operand prefetch depth 2-3.

template <int CTRL>
__device__ __forceinline__ float dpp_add(float v) {
    int o = __builtin_amdgcn_mov_dpp(__float_as_int(v), CTRL, 0xF, 0xF, true);
    return v + __int_as_float(o);
}
__device__ __forceinline__ float reduce16(float v) {
    v = dpp_add<0xB1>(v);
    v = dpp_add<0x4E>(v);
    v = dpp_add<0x141>(v);
    v = dpp_add<0x140>(v);
    return v;
}
__device__ __forceinline__ void reduce16x4(float& a, float& b, float& c, float& d) {
    a = dpp_add<0xB1>(a);  b = dpp_add<0xB1>(b);  c = dpp_add<0xB1>(c);  d = dpp_add<0xB1>(d);
    a = dpp_add<0x4E>(a);  b = dpp_add<0x4E>(b);  c = dpp_add<0x4E>(c);  d = dpp_add<0x4E>(d);
    a = dpp_add<0x141>(a); b = dpp_add<0x141>(b); c = dpp_add<0x141>(c); d = dpp_add<0x141>(d);
    a = dpp_add<0x140>(a); b = dpp_add<0x140>(b); c = dpp_add<0x140>(c); d = dpp_add<0x140>(d);
}
__device__ __forceinline__ float fast_sigmoid(float h) {   // sigmoid(h), h unscaled
    float e = __builtin_amdgcn_exp2f(h * NLOG2E);
    return __builtin_amdgcn_rcpf(1.0f + e);
}
__device__ __forceinline__ float dot4(const float* a, const float* b) {
    return fmaf(a[1], b[1], a[0] * b[0]) + fmaf(a[3], b[3], a[2] * b[2]);
}

#define SCH 16
#define NCH (T_STEPS / SCH)

__global__ __launch_bounds__(64, 1)
void scan16_kernel(const float* __restrict__ ws,
                   const float* __restrict__ S0,
                   const float* __restrict__ d_alpha,
                   float* __restrict__ out)
{
    const float* kb_ = ws;
    const float* vb_ = ws + TBN;
    const float* qb_ = ws + 2 * TBN;
    const float* ab_ = ws + 3 * TBN;   // pre-scaled: -log2e*(ax+b_alpha)

    __shared__ float kq[2][SCH][128];   // [0..63]=k_t, [64..127]=q_t
    __shared__ float va[2][SCH][8];     // [0..3]=v rows, [4..7]=ax rows
    __shared__ float ddt[SCH], eet[SCH];

    const int lane = threadIdx.x;
    // XCD swizzle (kept from r1: FETCH 131MB -> 16.7MB)
    const int bid = blockIdx.x;
    const int b   = (bid & 7) * 4 + ((bid >> 3) & 3);
    const int rg  = bid >> 5;
    const int rl  = lane >> 4;
    const int cl  = lane & 15;
    const int row = rg * 4 + rl;
    const int c0  = cl * 4;

    float S[4];
    {
        float4 sv = *(const float4*)(S0 + ((size_t)b * NST + row) * NST + c0);
        S[0] = sv.x; S[1] = sv.y; S[2] = sv.z; S[3] = sv.w;
    }
    const float da_s = d_alpha[row] * NLOG2E;

    const size_t stp = (size_t)BATCH * NST;   // 2048

    // staging maps (unchanged)
    int kqs[8], kqf[8];
    const float* kqg[8];
    #pragma unroll
    for (int p = 0; p < 8; p++) {
        const int idx = p * 64 + lane;
        const int s   = idx >> 5;
        const int f   = idx & 31;
        kqs[p] = s; kqf[p] = f;
        kqg[p] = ((f < 16) ? kb_ : qb_) + (size_t)s * stp + (size_t)b * NST + (f & 15) * 4;
    }
    const int vas = (lane & 31) >> 1;
    const int vaw = lane & 1;
    const float* vag = (vaw ? ab_ : vb_) + (size_t)vas * stp + (size_t)b * NST + rg * 4;

    auto issue = [&](int ch, float4 (&rk)[8], float4& rv) {
        const size_t off = (size_t)ch * SCH * stp;
        #pragma unroll
        for (int p = 0; p < 8; p++)
            rk[p] = *(const float4*)(kqg[p] + off);
        rv = *(const float4*)(vag + off);
    };
    auto commit = [&](int bi, const float4 (&rk)[8], const float4& rv) {
        #pragma unroll
        for (int p = 0; p < 8; p++)
            *(float4*)&kq[bi][kqs[p]][kqf[p] * 4] = rk[p];
        if (lane < 32)
            *(float4*)&va[bi][vas][vaw * 4] = rv;
    };

    // prologue: chunks 0,1 resident
    {
        float4 rk[8]; float4 rv;
        issue(0, rk, rv); commit(0, rk, rv);
        issue(1, rk, rv); commit(1, rk, rv);
    }

    // operand pipeline: kc=k_t, kn=k_{t+1}, kn2=k_{t+2}; q depth 2; v/ax depth 2
    float kc[4], kn[4], kn2[4];
    *(float4*)kc  = *(const float4*)&kq[0][0][c0];
    *(float4*)kn  = *(const float4*)&kq[0][1][c0];
    *(float4*)kn2 = *(const float4*)&kq[0][2][c0];
    float qf_c[4], qf_n[4];
    *(float4*)qf_c = *(const float4*)&kq[0][0][64 + c0];
    *(float4*)qf_n = *(const float4*)&kq[0][1][64 + c0];
    float vv_c = va[0][0][rl], aa_c = va[0][0][4 + rl];
    float vv_n = va[0][1][rl], aa_n = va[0][1][4 + rl];

    // chain state.  Invariant at top of step t:  ret_t = fma(a1, gg, u)
    // init (t=0): a1=1, gg=0, u=ret_0=S0.k_0; Q_1=S0.k_1 direct; w1 term killed via vprev=0.
    float a1 = 1.0f, oma1 = 0.0f, vprev = 0.0f, eev_carry = 0.0f;
    float gg = 0.0f;
    float u  = reduce16(dot4(S, kc));
    float RD = reduce16(dot4(S, kn));

    float hp[4];
    float* op = out + (size_t)b * NST + row;

    #pragma unroll 1
    for (int ch = 0; ch < NCH; ch++) {
        const int cur = ch & 1, nxt = cur ^ 1;

        float4 rk[8]; float4 rv;
        const int cn = (ch + 2 < NCH) ? ch + 2 : NCH - 1;
        issue(cn, rk, rv);

        // ---- per-chunk tables: dd[s]=k_s.k_{s+1}, ee[s]=k_s.k_{s+2} (granule-rotated) ----
        {
            const int tl = lane & 15;
            const int qg = lane >> 4;
            const float* k0p = &kq[cur][tl][0];
            const float* k1p = (tl < 15) ? &kq[cur][tl + 1][0] : &kq[nxt][0][0];
            const float* k2p = (tl < 14) ? &kq[cur][tl + 2][0] : &kq[nxt][tl - 14][0];
            float ds = 0.0f, es = 0.0f;
            #pragma unroll
            for (int i = 0; i < 4; i++) {
                const int g = ((qg * 4 + i + tl) & 15) * 4;
                float4 a  = *(const float4*)(k0p + g);
                float4 b1 = *(const float4*)(k1p + g);
                float4 c  = *(const float4*)(k2p + g);
                ds = fmaf(a.x, b1.x, ds); ds = fmaf(a.y, b1.y, ds);
                ds = fmaf(a.z, b1.z, ds); ds = fmaf(a.w, b1.w, ds);
                es = fmaf(a.x, c.x, es);  es = fmaf(a.y, c.y, es);
                es = fmaf(a.z, c.z, es);  es = fmaf(a.w, c.w, es);
            }
            ds += __shfl_xor(ds, 16); ds += __shfl_xor(ds, 32);
            es += __shfl_xor(es, 16); es += __shfl_xor(es, 32);
            if (lane < 16) { ddt[lane] = ds; eet[lane] = es; }
        }
        // tables -> registers (zero per-step table LDS traffic)
        float ddRa[16], eeRa[16];
        #pragma unroll
        for (int j = 0; j < 4; j++) {
            *(float4*)&ddRa[4*j] = *(const float4*)&ddt[4*j];
            *(float4*)&eeRa[4*j] = *(const float4*)&eet[4*j];
        }

        #pragma unroll
        for (int s = 0; s < SCH; s++) {
            const int t = ch * SCH + s;

            // --- chain head ---
            const float ret = fmaf(a1, gg, u);
            const float z   = fmaf(da_s, ret, aa_c);          // already -log2e scaled
            const float e   = __builtin_amdgcn_exp2f(z);

            // --- prefetch (independent; fills chain-stall slots) ---
            float k3[4], qn2[4], vv2, aa2;
            if (s + 3 < SCH) *(float4*)k3 = *(const float4*)&kq[cur][s + 3][c0];
            else             *(float4*)k3 = *(const float4*)&kq[nxt][s + 3 - SCH][c0];
            if (s + 2 < SCH) {
                *(float4*)qn2 = *(const float4*)&kq[cur][s + 2][64 + c0];
                vv2 = va[cur][s + 2][rl]; aa2 = va[cur][s + 2][4 + rl];
            } else {
                *(float4*)qn2 = *(const float4*)&kq[nxt][s + 2 - SCH][64 + c0];
                vv2 = va[nxt][s + 2 - SCH][rl]; aa2 = va[nxt][s + 2 - SCH][4 + rl];
            }

            // --- next-step chain inputs (depend on a1/oma1, NOT alpha_t) ---
            const float ddv = ddRa[s];
            const float eev = (s == 0) ? eev_carry : eeRa[s - 1];
            const float w1  = oma1 * vprev * eev;
            const float P   = fmaf(a1, RD, w1);               // P_{t+1}
            const float u_n = vv_c * ddv;                     // v_t * dd[t]
            const float gg_n = P - u_n;

            // --- Q partial for t+2 (uses S = S_{t-1} PRE-update, kn2 = k_{t+2}) ---
            float qp = dot4(S, kn2);
            const float RD_n = reduce16(qp);                  // consumed next step

            // --- chain tail ---
            const float alpha = __builtin_amdgcn_rcpf(1.0f + e);

            // --- S update ---
            const float oma = 1.0f - alpha;
            const float w   = oma * vv_c;
            S[0] = fmaf(alpha, S[0], w * kc[0]);
            S[1] = fmaf(alpha, S[1], w * kc[1]);
            S[2] = fmaf(alpha, S[2], w * kc[2]);
            S[3] = fmaf(alpha, S[3], w * kc[3]);

            // --- h partial; reduce+output batched 4-wide ---
            hp[s & 3] = dot4(S, qf_c);
            if ((s & 3) == 3) {
                float h0 = hp[0], h1 = hp[1], h2 = hp[2], h3 = hp[3];
                reduce16x4(h0, h1, h2, h3);
                const float o0 = h0 * h0 * fast_sigmoid(h0);
                const float o1 = h1 * h1 * fast_sigmoid(h1);
                const float o2 = h2 * h2 * fast_sigmoid(h2);
                const float o3 = h3 * h3 * fast_sigmoid(h3);
                if (cl == 0) {
                    op[(size_t)(t - 3) * stp] = o0;
                    op[(size_t)(t - 2) * stp] = o1;
                    op[(size_t)(t - 1) * stp] = o2;
                    op[(size_t)(t    ) * stp] = o3;
                }
            }

            // --- rotate pipeline ---
            a1 = alpha; oma1 = oma; vprev = vv_c;
            u = u_n; gg = gg_n;
            float RDt = RD_n; (void)RDt;
            // (assign after use above)
            // NOTE: RD consumed this step computing P; now advance it:
            // -- done via separate statement to keep liveness simple:
            // rotate operands
            kc[0] = kn[0];  kc[1] = kn[1];  kc[2] = kn[2];  kc[3] = kn[3];
            kn[0] = kn2[0]; kn[1] = kn2[1]; kn[2] = kn2[2]; kn[3] = kn2[3];
            kn2[0] = k3[0]; kn2[1] = k3[1]; kn2[2] = k3[2]; kn2[3] = k3[3];
            qf_c[0] = qf_n[0]; qf_c[1] = qf_n[1]; qf_c[2] = qf_n[2]; qf_c[3] = qf_n[3];
            qf_n[0] = qn2[0];  qf_n[1] = qn2[1];  qf_n[2] = qn2[2];  qf_n[3] = qn2[3];
            vv_c = vv_n; aa_c = aa_n; vv_n = vv2; aa_n = aa2;
            RD = RD_n;
        }

        eev_carry = eeRa[15];
        commit(cur, rk, rv);
    }

    // S_final
    float* sfp = out + TBN + ((size_t)b * NST + row) * NST + c0;
    *(float4*)sfp = make_float4(S[0], S[1], S[2], S[3]);
}

// ======================= launch =======================

extern "C" void kernel_launch(void* const* d_in, const int* in_sizes, int n_in,
                              void* d_out, int out_size, void* d_ws, size_t ws_size,
                              hipStream_t stream)
{
    const float* x  = (const float*)d_in[0];
    const float* S0 = (const float*)d_in[1];
    const float* Wk = (const float*)d_in[2];
    const float* Wv = (const float*)d_in[3];
    const float* Wq = (const float*)d_in[4];
    const float* Wa = (const float*)d_in[5];
    const float* da = (const float*)d_in[6];
    const float* ba = (const float*)d_in[7];
    float* out = (float*)d_out;
    float* ws  = (float*)d_ws;   // 4 x [T,B,N] fp32 = 32 MiB

    proj_gemm_v2<<<dim3((T_STEPS * BATCH) / 128), 512, 0, stream>>>(x, Wk, Wv, Wq, Wa, ba, ws);

    scan16_kernel<<<dim3(BATCH * 16), 64, 0, stream>>>(ws, S0, da, out);
}